// Round 1
// baseline (693.065 us; speedup 1.0000x reference)
//
#include <hip/hip_runtime.h>
#include <math.h>

#define B_ 4
#define L_ 2048
#define D_ 216
#define H_ 4
#define HD 54
#define M_ 64
#define LK (M_ + L_)   // 2112

// ---------------------------------------------------------------------------
// GEMM: C[rows,N] = A[rows,216] @ B[216,N].  BM=BN=64, BK=27 (216 = 8*27).
// 256 threads, each computes a 4x4 micro-tile.
// ---------------------------------------------------------------------------
__global__ __launch_bounds__(256) void gemm216(const float* __restrict__ A,
                                               const float* __restrict__ Bm,
                                               float* __restrict__ C, int N) {
    __shared__ __align__(16) float As[64][28];   // [row][k] pad 27->28
    __shared__ __align__(16) float Bs[27][68];   // [k][col] pad 64->68
    const int col0 = blockIdx.x * 64;
    const int row0 = blockIdx.y * 64;
    const int tid  = threadIdx.x;
    const int r0 = (tid >> 4) << 2;   // 0,4,...,60
    const int c0 = (tid & 15) << 2;   // 0,4,...,60
    float acc[4][4] = {};
    for (int k0 = 0; k0 < 216; k0 += 27) {
        if (k0) __syncthreads();
        for (int idx = tid; idx < 64 * 27; idx += 256) {
            int r = idx / 27, kk = idx % 27;
            As[r][kk] = A[(size_t)(row0 + r) * 216 + k0 + kk];
        }
        for (int idx = tid; idx < 27 * 64; idx += 256) {
            int kk = idx >> 6, c = idx & 63;
            Bs[kk][c] = (col0 + c < N) ? Bm[(size_t)(k0 + kk) * N + col0 + c] : 0.f;
        }
        __syncthreads();
        #pragma unroll
        for (int kk = 0; kk < 27; ++kk) {
            float a0 = As[r0 + 0][kk], a1 = As[r0 + 1][kk];
            float a2 = As[r0 + 2][kk], a3 = As[r0 + 3][kk];
            const float4 b4 = *reinterpret_cast<const float4*>(&Bs[kk][c0]);
            acc[0][0] += a0 * b4.x; acc[0][1] += a0 * b4.y; acc[0][2] += a0 * b4.z; acc[0][3] += a0 * b4.w;
            acc[1][0] += a1 * b4.x; acc[1][1] += a1 * b4.y; acc[1][2] += a1 * b4.z; acc[1][3] += a1 * b4.w;
            acc[2][0] += a2 * b4.x; acc[2][1] += a2 * b4.y; acc[2][2] += a2 * b4.z; acc[2][3] += a2 * b4.w;
            acc[3][0] += a3 * b4.x; acc[3][1] += a3 * b4.y; acc[3][2] += a3 * b4.z; acc[3][3] += a3 * b4.w;
        }
    }
    #pragma unroll
    for (int x = 0; x < 4; ++x) {
        #pragma unroll
        for (int y = 0; y < 4; ++y) {
            int c = col0 + c0 + y;
            if (c < N) C[(size_t)(row0 + r0 + x) * N + c] = acc[x][y];
        }
    }
}

// ---------------------------------------------------------------------------
// Scatter mem_k/mem_v [B,M,216] -> k_all/v_all [B,H,LK,54] rows 0..M-1
// ---------------------------------------------------------------------------
__global__ void memkv_copy(const float* __restrict__ mk, const float* __restrict__ mv,
                           float* __restrict__ kall, float* __restrict__ vall) {
    int idx = blockIdx.x * blockDim.x + threadIdx.x;
    if (idx >= B_ * M_ * D_) return;
    int b = idx / (M_ * D_);
    int rem = idx % (M_ * D_);
    int m = rem / D_, d = rem % D_;
    int h = d / HD, dd = d % HD;
    size_t off = ((size_t)(b * H_ + h) * LK + m) * HD + dd;
    kall[off] = mk[idx];
    vall[off] = mv[idx];
}

// ---------------------------------------------------------------------------
// RoPE + scale q, RoPE k, copy v.  One block per (b,l) row of qkv_raw.
// q -> qb [B,H,L,54] (pre-scaled by 54^-0.5), k/v -> rows M..M+L-1 of k_all/v_all
// ---------------------------------------------------------------------------
__global__ __launch_bounds__(128) void rope_scatter(const float* __restrict__ qkv,
                                                    float* __restrict__ qb,
                                                    float* __restrict__ kall,
                                                    float* __restrict__ vall) {
    const int blk = blockIdx.x;          // b*L + l
    const int b = blk / L_, l = blk % L_;
    const float* row = qkv + (size_t)blk * 648;
    const int t = threadIdx.x;
    const float scale = 0.13608276348795434f;  // 54^-0.5
    if (t < 108) {
        int h = t / 27, ii = t % 27;
        float inv = powf(10000.f, -(2.f * ii) / 54.f);
        float ang = (float)l * inv;
        float s = sinf(ang), c = cosf(ang);
        float q0v = row[h * HD + ii], q1v = row[h * HD + ii + 27];
        float k0v = row[D_ + h * HD + ii], k1v = row[D_ + h * HD + ii + 27];
        size_t qoff = ((size_t)(b * H_ + h) * L_ + l) * HD;
        qb[qoff + ii]      = (q0v * c - q1v * s) * scale;
        qb[qoff + ii + 27] = (q1v * c + q0v * s) * scale;
        size_t koff = ((size_t)(b * H_ + h) * LK + M_ + l) * HD;
        kall[koff + ii]      = k0v * c - k1v * s;
        kall[koff + ii + 27] = k1v * c + k0v * s;
    }
    for (int d = t; d < D_; d += 128) {
        int h = d / HD, dd = d % HD;
        vall[((size_t)(b * H_ + h) * LK + M_ + l) * HD + dd] = row[2 * D_ + d];
    }
}

// ---------------------------------------------------------------------------
// Flash attention.  Block = (qtile, b*H+h), 256 threads, TQ=TK=64.
// Tiles 0..q0/64 are causally full; tile q0/64+1 is the diagonal tile.
// ---------------------------------------------------------------------------
__global__ __launch_bounds__(256) void flash_attn(const float* __restrict__ qb,
                                                  const float* __restrict__ kall,
                                                  const float* __restrict__ vall,
                                                  const int* __restrict__ amask,
                                                  float* __restrict__ attn_out) {
    const int q0 = blockIdx.x * 64;
    const int bh = blockIdx.y;
    const int b = bh >> 2, h = bh & 3;
    __shared__ float Qs[64][57];
    __shared__ float Ks[64][57];
    __shared__ float Vs[64][57];
    __shared__ float Ss[64][65];
    __shared__ int maskS[64];
    const int tid = threadIdx.x;

    const float* qbase = qb + ((size_t)(b * H_ + h) * L_ + q0) * HD;
    for (int idx = tid; idx < 64 * HD; idx += 256) {
        int r = idx / HD, d = idx % HD;
        Qs[r][d] = qbase[idx];
    }
    // softmax/O ownership: row r = tid>>2, lane-in-row i = tid&3
    const int r = tid >> 2, i = tid & 3;
    // S micro-tile ownership (GEMM style)
    const int sr0 = (tid >> 4) << 2, sc0 = (tid & 15) << 2;

    float m_run = -1e30f, s_run = 0.f;
    float O[14];
    #pragma unroll
    for (int j = 0; j < 14; ++j) O[j] = 0.f;

    const int ntiles = q0 / 64 + 2;
    for (int t = 0; t < ntiles; ++t) {
        const int cbase = t * 64;
        __syncthreads();   // previous tile's PV reads done before overwriting K/V/S
        const float* kbase = kall + ((size_t)(b * H_ + h) * LK + cbase) * HD;
        const float* vbase = vall + ((size_t)(b * H_ + h) * LK + cbase) * HD;
        for (int idx = tid; idx < 64 * HD; idx += 256) {
            int rr = idx / HD, d = idx % HD;
            Ks[rr][d] = kbase[idx];
            Vs[rr][d] = vbase[idx];
        }
        if (tid < 64) {
            int cg = cbase + tid;
            maskS[tid] = (cg < M_) ? 1 : (amask[b * L_ + cg - M_] != 0);
        }
        __syncthreads();

        // S = Q K^T (4x4 per thread over hd=54)
        float acc[4][4] = {};
        for (int d = 0; d < HD; ++d) {
            float qa[4], kb[4];
            #pragma unroll
            for (int x = 0; x < 4; ++x) qa[x] = Qs[sr0 + x][d];
            #pragma unroll
            for (int y = 0; y < 4; ++y) kb[y] = Ks[sc0 + y][d];
            #pragma unroll
            for (int x = 0; x < 4; ++x)
                #pragma unroll
                for (int y = 0; y < 4; ++y) acc[x][y] += qa[x] * kb[y];
        }
        // mask + write S to LDS
        #pragma unroll
        for (int x = 0; x < 4; ++x) {
            #pragma unroll
            for (int y = 0; y < 4; ++y) {
                int cg = cbase + sc0 + y;
                int rg = q0 + sr0 + x;
                bool ok = maskS[sc0 + y] && !(cg >= M_ && (cg - M_) > rg);
                Ss[sr0 + x][sc0 + y] = ok ? acc[x][y] : -1e30f;
            }
        }
        __syncthreads();

        // online softmax: 4 threads per row, 16 cols each
        float mx = -1e30f;
        #pragma unroll
        for (int u = 0; u < 16; ++u) mx = fmaxf(mx, Ss[r][i * 16 + u]);
        mx = fmaxf(mx, __shfl_xor(mx, 1));
        mx = fmaxf(mx, __shfl_xor(mx, 2));
        float m_new = fmaxf(m_run, mx);
        float alpha = __expf(m_run - m_new);
        float lsum = 0.f;
        #pragma unroll
        for (int u = 0; u < 16; ++u) {
            float p = __expf(Ss[r][i * 16 + u] - m_new);
            Ss[r][i * 16 + u] = p;
            lsum += p;
        }
        lsum += __shfl_xor(lsum, 1);
        lsum += __shfl_xor(lsum, 2);
        s_run = s_run * alpha + lsum;
        m_run = m_new;
        __syncthreads();   // all P written before PV

        // O = O*alpha + P @ V   (thread owns cols c = i + 4j)
        #pragma unroll
        for (int j = 0; j < 14; ++j) O[j] *= alpha;
        for (int k = 0; k < 64; ++k) {
            float p = Ss[r][k];
            #pragma unroll
            for (int j = 0; j < 14; ++j) {
                int c = i + 4 * j;
                if (c < HD) O[j] += p * Vs[k][c];
            }
        }
    }

    // epilogue: normalize and write to [B,L,216] layout (col h*54+c)
    float invs = 1.f / s_run;
    float* obase = attn_out + ((size_t)b * L_ + q0 + r) * D_ + h * HD;
    #pragma unroll
    for (int j = 0; j < 14; ++j) {
        int c = i + 4 * j;
        if (c < HD) obase[c] = O[j] * invs;
    }
}

// ---------------------------------------------------------------------------
extern "C" void kernel_launch(void* const* d_in, const int* in_sizes, int n_in,
                              void* d_out, int out_size, void* d_ws, size_t ws_size,
                              hipStream_t stream) {
    const float* x     = (const float*)d_in[0];
    const float* mem_k = (const float*)d_in[1];
    const float* mem_v = (const float*)d_in[2];
    const int*   amask = (const int*)d_in[3];
    const float* Wqkv  = (const float*)d_in[4];
    const float* Wo    = (const float*)d_in[5];
    float* out = (float*)d_out;

    float* ws = (float*)d_ws;
    float* qkv_raw = ws;                                   // 8192*648
    float* qb   = qkv_raw + (size_t)8192 * 648;            // 16*2048*54
    float* kall = qb   + (size_t)16 * 2048 * 54;           // 16*2112*54
    float* vall = kall + (size_t)16 * 2112 * 54;           // 16*2112*54
    float* aout = vall + (size_t)16 * 2112 * 54;           // 8192*216

    // 1) qkv = x @ Wqkv   [8192 x 648]
    gemm216<<<dim3(11, 128), 256, 0, stream>>>(x, Wqkv, qkv_raw, 648);
    // 2) memory KV scatter
    memkv_copy<<<dim3((B_ * M_ * D_ + 255) / 256), 256, 0, stream>>>(mem_k, mem_v, kall, vall);
    // 3) RoPE + scatter
    rope_scatter<<<dim3(B_ * L_), 128, 0, stream>>>(qkv_raw, qb, kall, vall);
    // 4) flash attention
    flash_attn<<<dim3(L_ / 64, B_ * H_), 256, 0, stream>>>(qb, kall, vall, amask, aout);
    // 5) out = aout @ Wo  [8192 x 216]
    gemm216<<<dim3(4, 128), 256, 0, stream>>>(aout, Wo, out, 216);
}

// Round 2
// 230.463 us; speedup vs baseline: 3.0073x; 3.0073x over previous
//
#include <hip/hip_runtime.h>
#include <math.h>

#define B_ 4
#define L_ 2048
#define D_ 216
#define H_ 4
#define HD 54
#define HDP 64
#define M_ 64
#define LK 2112

typedef __attribute__((ext_vector_type(8))) __bf16 bf16x8;
typedef __attribute__((ext_vector_type(4))) float f32x4;

// ---------------------------------------------------------------------------
// fp32 GEMM: C[rows,N] = A[rows,216] @ B[216,N].  (kept from R1; MFMA next rd)
// ---------------------------------------------------------------------------
__global__ __launch_bounds__(256) void gemm216(const float* __restrict__ A,
                                               const float* __restrict__ Bm,
                                               float* __restrict__ C, int N) {
    __shared__ __align__(16) float As[64][28];
    __shared__ __align__(16) float Bs[27][68];
    const int col0 = blockIdx.x * 64;
    const int row0 = blockIdx.y * 64;
    const int tid  = threadIdx.x;
    const int r0 = (tid >> 4) << 2;
    const int c0 = (tid & 15) << 2;
    float acc[4][4] = {};
    for (int k0 = 0; k0 < 216; k0 += 27) {
        if (k0) __syncthreads();
        for (int idx = tid; idx < 64 * 27; idx += 256) {
            int r = idx / 27, kk = idx % 27;
            As[r][kk] = A[(size_t)(row0 + r) * 216 + k0 + kk];
        }
        for (int idx = tid; idx < 27 * 64; idx += 256) {
            int kk = idx >> 6, c = idx & 63;
            Bs[kk][c] = (col0 + c < N) ? Bm[(size_t)(k0 + kk) * N + col0 + c] : 0.f;
        }
        __syncthreads();
        #pragma unroll
        for (int kk = 0; kk < 27; ++kk) {
            float a0 = As[r0 + 0][kk], a1 = As[r0 + 1][kk];
            float a2 = As[r0 + 2][kk], a3 = As[r0 + 3][kk];
            const float4 b4 = *reinterpret_cast<const float4*>(&Bs[kk][c0]);
            acc[0][0] += a0 * b4.x; acc[0][1] += a0 * b4.y; acc[0][2] += a0 * b4.z; acc[0][3] += a0 * b4.w;
            acc[1][0] += a1 * b4.x; acc[1][1] += a1 * b4.y; acc[1][2] += a1 * b4.z; acc[1][3] += a1 * b4.w;
            acc[2][0] += a2 * b4.x; acc[2][1] += a2 * b4.y; acc[2][2] += a2 * b4.z; acc[2][3] += a2 * b4.w;
            acc[3][0] += a3 * b4.x; acc[3][1] += a3 * b4.y; acc[3][2] += a3 * b4.z; acc[3][3] += a3 * b4.w;
        }
    }
    #pragma unroll
    for (int x = 0; x < 4; ++x)
        #pragma unroll
        for (int y = 0; y < 4; ++y) {
            int c = col0 + c0 + y;
            if (c < N) C[(size_t)(row0 + r0 + x) * N + c] = acc[x][y];
        }
}

// ---------------------------------------------------------------------------
// mem_k/mem_v -> kall rows 0..M-1 (bf16, d-padded to 64) and vt cols 0..M-1
// ---------------------------------------------------------------------------
__global__ void memkv_pack(const float* __restrict__ mk, const float* __restrict__ mv,
                           __bf16* __restrict__ kall, __bf16* __restrict__ vt) {
    int idx = blockIdx.x * 256 + threadIdx.x;
    if (idx >= B_ * M_ * H_ * 64) return;
    int b  = idx >> 14;
    int m  = (idx >> 8) & 63;
    int h  = (idx >> 6) & 3;
    int dd = idx & 63;
    float kv = (dd < HD) ? mk[((size_t)(b * M_ + m)) * D_ + h * HD + dd] : 0.f;
    kall[((size_t)(b * 4 + h) * LK + m) * HDP + dd] = (__bf16)kv;
    if (dd < HD)
        vt[((size_t)(b * 4 + h) * HD + dd) * LK + m] =
            (__bf16)mv[((size_t)(b * M_ + m)) * D_ + h * HD + dd];
}

// ---------------------------------------------------------------------------
// RoPE q (pre-scaled) and k -> bf16 [B*H, rows, 64], zero-padded d 54..63
// ---------------------------------------------------------------------------
__global__ __launch_bounds__(128) void rope_pack(const float* __restrict__ qkv,
                                                 __bf16* __restrict__ qb,
                                                 __bf16* __restrict__ kall) {
    const int blk = blockIdx.x;
    const int b = blk / L_, l = blk % L_;
    const float* row = qkv + (size_t)blk * 648;
    const int t = threadIdx.x;
    const float scale = 0.13608276348795434f;  // 54^-0.5
    if (t < 108) {
        int h = t / 27, ii = t % 27;
        float inv = powf(10000.f, -(2.f * ii) / 54.f);
        float ang = (float)l * inv;
        float s = sinf(ang), c = cosf(ang);
        float q0v = row[h * HD + ii], q1v = row[h * HD + ii + 27];
        float k0v = row[D_ + h * HD + ii], k1v = row[D_ + h * HD + ii + 27];
        size_t qoff = ((size_t)(b * 4 + h) * L_ + l) * HDP;
        qb[qoff + ii]      = (__bf16)((q0v * c - q1v * s) * scale);
        qb[qoff + ii + 27] = (__bf16)((q1v * c + q0v * s) * scale);
        size_t koff = ((size_t)(b * 4 + h) * LK + M_ + l) * HDP;
        kall[koff + ii]      = (__bf16)(k0v * c - k1v * s);
        kall[koff + ii + 27] = (__bf16)(k1v * c + k0v * s);
    }
    for (int p = t; p < 40; p += 128) {
        int h = p / 10, dd = 54 + p % 10;
        qb[((size_t)(b * 4 + h) * L_ + l) * HDP + dd] = (__bf16)0.f;
        kall[((size_t)(b * 4 + h) * LK + M_ + l) * HDP + dd] = (__bf16)0.f;
    }
}

// ---------------------------------------------------------------------------
// v part of qkv -> vt [B*H, 54, LK] (transposed, bf16) via LDS tile
// ---------------------------------------------------------------------------
__global__ __launch_bounds__(256) void transpose_v(const float* __restrict__ qkv,
                                                   __bf16* __restrict__ vt) {
    const int l0 = blockIdx.x * 64;
    const int b = blockIdx.y;
    __shared__ float T[64][55];
    for (int h = 0; h < 4; ++h) {
        __syncthreads();
        for (int idx = threadIdx.x; idx < 64 * 54; idx += 256) {
            int l = idx / 54, d = idx % 54;
            T[l][d] = qkv[((size_t)(b * L_ + l0 + l)) * 648 + 432 + h * 54 + d];
        }
        __syncthreads();
        for (int idx = threadIdx.x; idx < 54 * 64; idx += 256) {
            int d = idx >> 6, l = idx & 63;
            vt[((size_t)(b * 4 + h) * HD + d) * LK + M_ + l0 + l] = (__bf16)T[l][d];
        }
    }
}

// ---------------------------------------------------------------------------
// combined padding-mask bias [B, LK]: 0 valid, -1e30 masked
// ---------------------------------------------------------------------------
__global__ void mask_bias(const int* __restrict__ amask, float* __restrict__ bias) {
    int idx = blockIdx.x * 256 + threadIdx.x;
    if (idx >= B_ * LK) return;
    int b = idx / LK, c = idx % LK;
    bias[idx] = (c < M_ || amask[b * L_ + c - M_] != 0) ? 0.f : -1e30f;
}

// ---------------------------------------------------------------------------
// MFMA flash attention: 64 q-rows/block, 4 waves x 16-row strips, K-tile 64.
// All LDS tiles XOR-swizzled: element k stored at k ^ ((row&7)<<3).
// ---------------------------------------------------------------------------
__global__ __launch_bounds__(256) void flash_mfma(const __bf16* __restrict__ qb,
                                                  const __bf16* __restrict__ kall,
                                                  const __bf16* __restrict__ vt,
                                                  const float* __restrict__ bias,
                                                  float* __restrict__ aout) {
    const int q0 = blockIdx.x * 64;
    const int bh = blockIdx.y;
    const int b = bh >> 2, h = bh & 3;
    __shared__ __align__(16) __bf16 Qs[4096];
    __shared__ __align__(16) __bf16 Ks[4096];
    __shared__ __align__(16) __bf16 Vs[4096];
    __shared__ __align__(16) __bf16 Ps[4096];

    const int tid = threadIdx.x;
    const int lane = tid & 63;
    const int w = tid >> 6;
    const int l15 = lane & 15;
    const int l4 = lane >> 4;

    // stage Q tile (swizzled)
    {
        const __bf16* src = qb + ((size_t)bh * L_ + q0) * HDP;
        for (int ch = tid; ch < 512; ch += 256) {
            int row = ch >> 3, c8 = ch & 7;
            bf16x8 v = *reinterpret_cast<const bf16x8*>(src + ch * 8);
            *reinterpret_cast<bf16x8*>(&Qs[row * 64 + ((c8 ^ (row & 7)) * 8)]) = v;
        }
    }
    __syncthreads();
    bf16x8 aQ[2];
    {
        int qrow = 16 * w + l15, s = (qrow & 7) << 3;
        aQ[0] = *reinterpret_cast<const bf16x8*>(&Qs[qrow * 64 + ((l4 * 8) ^ s)]);
        aQ[1] = *reinterpret_cast<const bf16x8*>(&Qs[qrow * 64 + ((32 + l4 * 8) ^ s)]);
    }

    f32x4 Oacc[4];
    float m_run[4], l_run[4];
    #pragma unroll
    for (int nt = 0; nt < 4; ++nt) Oacc[nt] = (f32x4){0.f, 0.f, 0.f, 0.f};
    #pragma unroll
    for (int r = 0; r < 4; ++r) { m_run[r] = -1e30f; l_run[r] = 0.f; }

    const int ntiles = q0 / 64 + 2;
    const int rgbase = q0 + 16 * w + l4 * 4;  // + r gives global q row

    for (int t = 0; t < ntiles; ++t) {
        const int cbase = t * 64;
        __syncthreads();
        {   // stage K tile (contiguous 8KB) + Vt tile, swizzled
            const __bf16* ksrc = kall + ((size_t)bh * LK + cbase) * HDP;
            for (int ch = tid; ch < 512; ch += 256) {
                int row = ch >> 3, c8 = ch & 7;
                bf16x8 v = *reinterpret_cast<const bf16x8*>(ksrc + ch * 8);
                *reinterpret_cast<bf16x8*>(&Ks[row * 64 + ((c8 ^ (row & 7)) * 8)]) = v;
            }
            for (int ch = tid; ch < 512; ch += 256) {
                int d = ch >> 3, c8 = ch & 7;
                bf16x8 v{};
                if (d < HD)
                    v = *reinterpret_cast<const bf16x8*>(
                        vt + ((size_t)bh * HD + d) * LK + cbase + c8 * 8);
                *reinterpret_cast<bf16x8*>(&Vs[d * 64 + ((c8 ^ (d & 7)) * 8)]) = v;
            }
        }
        __syncthreads();

        // S = Q K^T  (per wave: 16 q rows x 64 cols)
        f32x4 S[4];
        #pragma unroll
        for (int nt = 0; nt < 4; ++nt) {
            int krow = nt * 16 + l15, s = (krow & 7) << 3;
            bf16x8 b0 = *reinterpret_cast<const bf16x8*>(&Ks[krow * 64 + ((l4 * 8) ^ s)]);
            bf16x8 b1 = *reinterpret_cast<const bf16x8*>(&Ks[krow * 64 + ((32 + l4 * 8) ^ s)]);
            f32x4 acc = (f32x4){0.f, 0.f, 0.f, 0.f};
            acc = __builtin_amdgcn_mfma_f32_16x16x32_bf16(aQ[0], b0, acc, 0, 0, 0);
            acc = __builtin_amdgcn_mfma_f32_16x16x32_bf16(aQ[1], b1, acc, 0, 0, 0);
            S[nt] = acc;
        }
        // masks: additive bias (padding) + causal compare
        float bias4[4];
        #pragma unroll
        for (int nt = 0; nt < 4; ++nt)
            bias4[nt] = bias[b * LK + cbase + nt * 16 + l15];
        #pragma unroll
        for (int nt = 0; nt < 4; ++nt) {
            int cg = cbase + nt * 16 + l15;
            #pragma unroll
            for (int r = 0; r < 4; ++r) {
                float sv = S[nt][r] + bias4[nt];
                S[nt][r] = (cg > rgbase + r + M_) ? -1e30f : sv;
            }
        }
        // online softmax (row lives in one 16-lane group; 4 rows/lane as regs)
        float mt[4], alpha[4], ls[4];
        #pragma unroll
        for (int r = 0; r < 4; ++r)
            mt[r] = fmaxf(fmaxf(S[0][r], S[1][r]), fmaxf(S[2][r], S[3][r]));
        #pragma unroll
        for (int r = 0; r < 4; ++r) {
            mt[r] = fmaxf(mt[r], __shfl_xor(mt[r], 1));
            mt[r] = fmaxf(mt[r], __shfl_xor(mt[r], 2));
            mt[r] = fmaxf(mt[r], __shfl_xor(mt[r], 4));
            mt[r] = fmaxf(mt[r], __shfl_xor(mt[r], 8));
            float m_new = fmaxf(m_run[r], mt[r]);
            alpha[r] = __expf(m_run[r] - m_new);
            m_run[r] = m_new;
            ls[r] = 0.f;
        }
        #pragma unroll
        for (int nt = 0; nt < 4; ++nt)
            #pragma unroll
            for (int r = 0; r < 4; ++r) {
                float p = __expf(S[nt][r] - m_run[r]);
                S[nt][r] = p;
                ls[r] += p;
            }
        #pragma unroll
        for (int r = 0; r < 4; ++r) {
            ls[r] += __shfl_xor(ls[r], 1);
            ls[r] += __shfl_xor(ls[r], 2);
            ls[r] += __shfl_xor(ls[r], 4);
            ls[r] += __shfl_xor(ls[r], 8);
            l_run[r] = l_run[r] * alpha[r] + ls[r];
        }
        // write P (bf16) into wave-private strip of Ps (swizzled)
        #pragma unroll
        for (int r = 0; r < 4; ++r) {
            int row = 16 * w + l4 * 4 + r, s = (row & 7) << 3;
            #pragma unroll
            for (int nt = 0; nt < 4; ++nt) {
                int col = nt * 16 + l15;
                Ps[row * 64 + (col ^ s)] = (__bf16)S[nt][r];
            }
        }
        // rescale O
        #pragma unroll
        for (int nt = 0; nt < 4; ++nt)
            #pragma unroll
            for (int r = 0; r < 4; ++r) Oacc[nt][r] *= alpha[r];
        // PV
        bf16x8 aP[2];
        {
            int prow = 16 * w + l15, s = (prow & 7) << 3;
            aP[0] = *reinterpret_cast<const bf16x8*>(&Ps[prow * 64 + ((l4 * 8) ^ s)]);
            aP[1] = *reinterpret_cast<const bf16x8*>(&Ps[prow * 64 + ((32 + l4 * 8) ^ s)]);
        }
        #pragma unroll
        for (int nt = 0; nt < 4; ++nt) {
            int vrow = nt * 16 + l15, s = (vrow & 7) << 3;
            bf16x8 v0 = *reinterpret_cast<const bf16x8*>(&Vs[vrow * 64 + ((l4 * 8) ^ s)]);
            bf16x8 v1 = *reinterpret_cast<const bf16x8*>(&Vs[vrow * 64 + ((32 + l4 * 8) ^ s)]);
            Oacc[nt] = __builtin_amdgcn_mfma_f32_16x16x32_bf16(aP[0], v0, Oacc[nt], 0, 0, 0);
            Oacc[nt] = __builtin_amdgcn_mfma_f32_16x16x32_bf16(aP[1], v1, Oacc[nt], 0, 0, 0);
        }
    }

    // epilogue: normalize, write fp32 [B, L, 216]
    float invl[4];
    #pragma unroll
    for (int r = 0; r < 4; ++r) invl[r] = 1.f / l_run[r];
    #pragma unroll
    for (int nt = 0; nt < 4; ++nt) {
        int c = nt * 16 + l15;
        if (c < HD) {
            #pragma unroll
            for (int r = 0; r < 4; ++r)
                aout[((size_t)b * L_ + rgbase + r) * D_ + h * HD + c] = Oacc[nt][r] * invl[r];
        }
    }
}

// ---------------------------------------------------------------------------
extern "C" void kernel_launch(void* const* d_in, const int* in_sizes, int n_in,
                              void* d_out, int out_size, void* d_ws, size_t ws_size,
                              hipStream_t stream) {
    const float* x     = (const float*)d_in[0];
    const float* mem_k = (const float*)d_in[1];
    const float* mem_v = (const float*)d_in[2];
    const int*   amask = (const int*)d_in[3];
    const float* Wqkv  = (const float*)d_in[4];
    const float* Wo    = (const float*)d_in[5];
    float* out = (float*)d_out;

    float* qkv_raw = (float*)d_ws;                       // 8192*648
    float* aout    = qkv_raw + (size_t)8192 * 648;       // 8192*216
    float* bias    = aout + (size_t)8192 * 216;          // 4*2112
    __bf16* qb   = (__bf16*)(bias + 8448);               // 16*2048*64
    __bf16* kall = qb + (size_t)16 * 2048 * 64;          // 16*2112*64
    __bf16* vt   = kall + (size_t)16 * 2112 * 64;        // 16*54*2112

    gemm216<<<dim3(11, 128), 256, 0, stream>>>(x, Wqkv, qkv_raw, 648);
    memkv_pack<<<dim3((B_ * M_ * H_ * 64 + 255) / 256), 256, 0, stream>>>(mem_k, mem_v, kall, vt);
    rope_pack<<<dim3(B_ * L_), 128, 0, stream>>>(qkv_raw, qb, kall);
    transpose_v<<<dim3(L_ / 64, B_), 256, 0, stream>>>(qkv_raw, vt);
    mask_bias<<<dim3((B_ * LK + 255) / 256), 256, 0, stream>>>(amask, bias);
    flash_mfma<<<dim3(L_ / 64, B_ * H_), 256, 0, stream>>>(qb, kall, vt, bias, aout);
    gemm216<<<dim3(4, 128), 256, 0, stream>>>(aout, Wo, out, 216);
}

// Round 3
// 116.571 us; speedup vs baseline: 5.9454x; 1.9770x over previous
//
#include <hip/hip_runtime.h>
#include <math.h>

#define B_ 4
#define L_ 2048
#define D_ 216
#define H_ 4
#define HD 54
#define HDP 64
#define M_ 64
#define LK 2112
#define KP 256   // padded K for MFMA GEMMs

typedef __attribute__((ext_vector_type(8))) __bf16 bf16x8;
typedef __attribute__((ext_vector_type(4))) float f32x4;

// ---------------------------------------------------------------------------
// x [8192][216] fp32 -> xb [8192][256] bf16 (zero-padded)
// ---------------------------------------------------------------------------
__global__ void conv_x(const float* __restrict__ x, __bf16* __restrict__ xb) {
    int idx = blockIdx.x * 256 + threadIdx.x;   // 8192*32 chunks of 8
    int row = idx >> 5, c8 = idx & 31;
    bf16x8 v{};
    if (c8 < 27) {
        const float* p = x + (size_t)row * 216 + c8 * 8;
        #pragma unroll
        for (int j = 0; j < 8; ++j) v[j] = (__bf16)p[j];
    }
    *reinterpret_cast<bf16x8*>(xb + (size_t)row * KP + c8 * 8) = v;
}

// ---------------------------------------------------------------------------
// W [Kin][Nin] fp32 -> Wt [Npad][256] bf16 transposed, zero-padded
// ---------------------------------------------------------------------------
__global__ void conv_wt(const float* __restrict__ W, __bf16* __restrict__ Wt,
                        int Kin, int Nin, int Npad) {
    int idx = blockIdx.x * 256 + threadIdx.x;
    if (idx >= Npad * KP) return;
    int n = idx >> 8, k = idx & 255;
    float v = (n < Nin && k < Kin) ? W[(size_t)k * Nin + n] : 0.f;
    Wt[idx] = (__bf16)v;
}

// ---------------------------------------------------------------------------
// bf16 MFMA GEMM: C[8192][N] fp32 = A[8192][256] @ Bt[Npad][256]^T
// BM=128 BN=64 BK=64, 4 waves (2M x 2N), XOR-swizzled LDS, reg-staged.
// ---------------------------------------------------------------------------
__global__ __launch_bounds__(256) void gemm_mfma(const __bf16* __restrict__ A,
                                                 const __bf16* __restrict__ Bt,
                                                 float* __restrict__ C, int N) {
    __shared__ __align__(16) __bf16 As[8192];   // [128][64] swizzled
    __shared__ __align__(16) __bf16 Bs[4096];   // [64][64] swizzled
    const int col0 = blockIdx.x * 64;
    const int row0 = blockIdx.y * 128;
    const int tid = threadIdx.x;
    const int lane = tid & 63;
    const int w = tid >> 6, wm = w >> 1, wn = w & 1;
    const int l15 = lane & 15, l4 = lane >> 4;

    f32x4 acc[4][2];
    #pragma unroll
    for (int m = 0; m < 4; ++m)
        #pragma unroll
        for (int n = 0; n < 2; ++n) acc[m][n] = (f32x4){0.f, 0.f, 0.f, 0.f};

    bf16x8 ra[4], rb[2];
    #pragma unroll
    for (int i = 0; i < 4; ++i) { int c = tid + 256 * i, r = c >> 3, c8 = c & 7;
        ra[i] = *reinterpret_cast<const bf16x8*>(A + (size_t)(row0 + r) * KP + c8 * 8); }
    #pragma unroll
    for (int i = 0; i < 2; ++i) { int c = tid + 256 * i, r = c >> 3, c8 = c & 7;
        rb[i] = *reinterpret_cast<const bf16x8*>(Bt + (size_t)(col0 + r) * KP + c8 * 8); }

    for (int kit = 0; kit < 4; ++kit) {
        __syncthreads();   // prior compute done reading LDS
        #pragma unroll
        for (int i = 0; i < 4; ++i) { int c = tid + 256 * i, r = c >> 3, c8 = c & 7;
            *reinterpret_cast<bf16x8*>(&As[r * 64 + ((c8 ^ (r & 7)) * 8)]) = ra[i]; }
        #pragma unroll
        for (int i = 0; i < 2; ++i) { int c = tid + 256 * i, r = c >> 3, c8 = c & 7;
            *reinterpret_cast<bf16x8*>(&Bs[r * 64 + ((c8 ^ (r & 7)) * 8)]) = rb[i]; }
        __syncthreads();
        if (kit < 3) {
            const int k0 = (kit + 1) * 64;
            #pragma unroll
            for (int i = 0; i < 4; ++i) { int c = tid + 256 * i, r = c >> 3, c8 = c & 7;
                ra[i] = *reinterpret_cast<const bf16x8*>(A + (size_t)(row0 + r) * KP + k0 + c8 * 8); }
            #pragma unroll
            for (int i = 0; i < 2; ++i) { int c = tid + 256 * i, r = c >> 3, c8 = c & 7;
                rb[i] = *reinterpret_cast<const bf16x8*>(Bt + (size_t)(col0 + r) * KP + k0 + c8 * 8); }
        }
        #pragma unroll
        for (int ks = 0; ks < 2; ++ks) {
            bf16x8 af[4], bfr[2];
            #pragma unroll
            for (int m = 0; m < 4; ++m) { int row = wm * 64 + m * 16 + l15; int ch = ks * 4 + l4;
                af[m] = *reinterpret_cast<const bf16x8*>(&As[row * 64 + ((ch ^ (row & 7)) * 8)]); }
            #pragma unroll
            for (int n = 0; n < 2; ++n) { int row = wn * 32 + n * 16 + l15; int ch = ks * 4 + l4;
                bfr[n] = *reinterpret_cast<const bf16x8*>(&Bs[row * 64 + ((ch ^ (row & 7)) * 8)]); }
            #pragma unroll
            for (int m = 0; m < 4; ++m)
                #pragma unroll
                for (int n = 0; n < 2; ++n)
                    acc[m][n] = __builtin_amdgcn_mfma_f32_16x16x32_bf16(af[m], bfr[n], acc[m][n], 0, 0, 0);
        }
    }
    #pragma unroll
    for (int m = 0; m < 4; ++m)
        #pragma unroll
        for (int n = 0; n < 2; ++n) {
            int cc = col0 + wn * 32 + n * 16 + l15;
            if (cc < N) {
                #pragma unroll
                for (int rr = 0; rr < 4; ++rr)
                    C[(size_t)(row0 + wm * 64 + m * 16 + l4 * 4 + rr) * N + cc] = acc[m][n][rr];
            }
        }
}

// ---------------------------------------------------------------------------
// mem_k/mem_v -> kall rows 0..M-1 (bf16, padded) and vt cols 0..M-1
// ---------------------------------------------------------------------------
__global__ void memkv_pack(const float* __restrict__ mk, const float* __restrict__ mv,
                           __bf16* __restrict__ kall, __bf16* __restrict__ vt) {
    int idx = blockIdx.x * 256 + threadIdx.x;
    if (idx >= B_ * M_ * H_ * 64) return;
    int b  = idx >> 14;
    int m  = (idx >> 8) & 63;
    int h  = (idx >> 6) & 3;
    int dd = idx & 63;
    float kv = (dd < HD) ? mk[((size_t)(b * M_ + m)) * D_ + h * HD + dd] : 0.f;
    kall[((size_t)(b * 4 + h) * LK + m) * HDP + dd] = (__bf16)kv;
    if (dd < HD)
        vt[((size_t)(b * 4 + h) * HD + dd) * LK + m] =
            (__bf16)mv[((size_t)(b * M_ + m)) * D_ + h * HD + dd];
}

// ---------------------------------------------------------------------------
// RoPE q (pre-scaled) and k -> bf16 [B*H, rows, 64], zero-padded d 54..63
// ---------------------------------------------------------------------------
__global__ __launch_bounds__(128) void rope_pack(const float* __restrict__ qkv,
                                                 __bf16* __restrict__ qb,
                                                 __bf16* __restrict__ kall) {
    const int blk = blockIdx.x;
    const int b = blk / L_, l = blk % L_;
    const float* row = qkv + (size_t)blk * 648;
    const int t = threadIdx.x;
    const float scale = 0.13608276348795434f;  // 54^-0.5
    if (t < 108) {
        int h = t / 27, ii = t % 27;
        float inv = exp2f(-0.49213749924f * (float)ii);  // 10000^(-2i/54)
        float ang = (float)l * inv;
        float s = sinf(ang), c = cosf(ang);
        float q0v = row[h * HD + ii], q1v = row[h * HD + ii + 27];
        float k0v = row[D_ + h * HD + ii], k1v = row[D_ + h * HD + ii + 27];
        size_t qoff = ((size_t)(b * 4 + h) * L_ + l) * HDP;
        qb[qoff + ii]      = (__bf16)((q0v * c - q1v * s) * scale);
        qb[qoff + ii + 27] = (__bf16)((q1v * c + q0v * s) * scale);
        size_t koff = ((size_t)(b * 4 + h) * LK + M_ + l) * HDP;
        kall[koff + ii]      = (__bf16)(k0v * c - k1v * s);
        kall[koff + ii + 27] = (__bf16)(k1v * c + k0v * s);
    }
    for (int p = t; p < 40; p += 128) {
        int h = p / 10, dd = 54 + p % 10;
        qb[((size_t)(b * 4 + h) * L_ + l) * HDP + dd] = (__bf16)0.f;
        kall[((size_t)(b * 4 + h) * LK + M_ + l) * HDP + dd] = (__bf16)0.f;
    }
}

// ---------------------------------------------------------------------------
// v part of qkv -> vt [B*H, 54, LK] (transposed, bf16) via LDS tile
// ---------------------------------------------------------------------------
__global__ __launch_bounds__(256) void transpose_v(const float* __restrict__ qkv,
                                                   __bf16* __restrict__ vt) {
    const int l0 = blockIdx.x * 64;
    const int b = blockIdx.y;
    __shared__ float T[64][55];
    for (int h = 0; h < 4; ++h) {
        __syncthreads();
        for (int idx = threadIdx.x; idx < 64 * 54; idx += 256) {
            int l = idx / 54, d = idx % 54;
            T[l][d] = qkv[((size_t)(b * L_ + l0 + l)) * 648 + 432 + h * 54 + d];
        }
        __syncthreads();
        for (int idx = threadIdx.x; idx < 54 * 64; idx += 256) {
            int d = idx >> 6, l = idx & 63;
            vt[((size_t)(b * 4 + h) * HD + d) * LK + M_ + l0 + l] = (__bf16)T[l][d];
        }
    }
}

// ---------------------------------------------------------------------------
// combined padding-mask bias [B, LK]: 0 valid, -1e30 masked
// ---------------------------------------------------------------------------
__global__ void mask_bias(const int* __restrict__ amask, float* __restrict__ bias) {
    int idx = blockIdx.x * 256 + threadIdx.x;
    if (idx >= B_ * LK) return;
    int b = idx / LK, c = idx % LK;
    bias[idx] = (c < M_ || amask[b * L_ + c - M_] != 0) ? 0.f : -1e30f;
}

// ---------------------------------------------------------------------------
// MFMA flash attention. Complementary q-tile map for CU load balance;
// T14 async-stage split (global->reg early, ds_write late); bias via LDS.
// Writes bf16 output into padded [8192][256] buffer for the Wo MFMA GEMM.
// ---------------------------------------------------------------------------
__global__ __launch_bounds__(256) void flash_mfma(const __bf16* __restrict__ qb,
                                                  const __bf16* __restrict__ kall,
                                                  const __bf16* __restrict__ vt,
                                                  const float* __restrict__ bias,
                                                  __bf16* __restrict__ aoutb) {
    const int qt = (blockIdx.y & 8) ? (31 - (int)blockIdx.x) : (int)blockIdx.x;
    const int q0 = qt * 64;
    const int bh = blockIdx.y;
    const int b = bh >> 2, h = bh & 3;
    __shared__ __align__(16) __bf16 Qs[4096];
    __shared__ __align__(16) __bf16 Ks[4096];
    __shared__ __align__(16) __bf16 Vs[4096];
    __shared__ __align__(16) __bf16 Ps[4096];
    __shared__ float biasS[64];

    const int tid = threadIdx.x;
    const int lane = tid & 63;
    const int w = tid >> 6;
    const int l15 = lane & 15;
    const int l4 = lane >> 4;

    // stage Q (swizzled) + zero V pad rows (written once, never overwritten)
    {
        const __bf16* src = qb + ((size_t)bh * L_ + q0) * HDP;
        for (int ch = tid; ch < 512; ch += 256) {
            int row = ch >> 3, c8 = ch & 7;
            bf16x8 v = *reinterpret_cast<const bf16x8*>(src + ch * 8);
            *reinterpret_cast<bf16x8*>(&Qs[row * 64 + ((c8 ^ (row & 7)) * 8)]) = v;
        }
        if (tid < 80) {
            int d = 54 + (tid >> 3), c8 = tid & 7;
            bf16x8 z{};
            *reinterpret_cast<bf16x8*>(&Vs[d * 64 + ((c8 ^ (d & 7)) * 8)]) = z;
        }
    }

    const int ntiles = qt + 2;
    const int rgbase = q0 + 16 * w + l4 * 4;
    const __bf16* kbase = kall + (size_t)bh * LK * HDP;
    const __bf16* vbase = vt + (size_t)bh * HD * LK;

    // prefetch tile 0 into registers
    bf16x8 rk[2], rv[2];
    float biasR = 0.f;
    {
        rk[0] = *reinterpret_cast<const bf16x8*>(kbase + tid * 8);
        rk[1] = *reinterpret_cast<const bf16x8*>(kbase + (tid + 256) * 8);
        { int d = tid >> 3, c8 = tid & 7;
          rv[0] = *reinterpret_cast<const bf16x8*>(vbase + (size_t)d * LK + c8 * 8); }
        if (tid < 176) { int c = tid + 256, d = c >> 3, c8 = c & 7;
          rv[1] = *reinterpret_cast<const bf16x8*>(vbase + (size_t)d * LK + c8 * 8); }
        if (tid < 64) biasR = bias[b * LK + tid];
    }

    __syncthreads();   // Q + V-pad visible
    bf16x8 aQ[2];
    {
        int qrow = 16 * w + l15, s = (qrow & 7) << 3;
        aQ[0] = *reinterpret_cast<const bf16x8*>(&Qs[qrow * 64 + ((l4 * 8) ^ s)]);
        aQ[1] = *reinterpret_cast<const bf16x8*>(&Qs[qrow * 64 + ((32 + l4 * 8) ^ s)]);
    }

    f32x4 Oacc[4];
    float m_run[4], l_run[4];
    #pragma unroll
    for (int nt = 0; nt < 4; ++nt) Oacc[nt] = (f32x4){0.f, 0.f, 0.f, 0.f};
    #pragma unroll
    for (int r = 0; r < 4; ++r) { m_run[r] = -1e30f; l_run[r] = 0.f; }

    for (int t = 0; t < ntiles; ++t) {
        const int cbase = t * 64;
        __syncthreads();   // prior compute done reading Ks/Vs
        // commit staged registers to LDS (swizzled)
        { int r = tid >> 3, c8 = tid & 7;
          *reinterpret_cast<bf16x8*>(&Ks[r * 64 + ((c8 ^ (r & 7)) * 8)]) = rk[0]; }
        { int c = tid + 256, r = c >> 3, c8 = c & 7;
          *reinterpret_cast<bf16x8*>(&Ks[r * 64 + ((c8 ^ (r & 7)) * 8)]) = rk[1]; }
        { int d = tid >> 3, c8 = tid & 7;
          *reinterpret_cast<bf16x8*>(&Vs[d * 64 + ((c8 ^ (d & 7)) * 8)]) = rv[0]; }
        if (tid < 176) { int c = tid + 256, d = c >> 3, c8 = c & 7;
          *reinterpret_cast<bf16x8*>(&Vs[d * 64 + ((c8 ^ (d & 7)) * 8)]) = rv[1]; }
        if (tid < 64) biasS[tid] = biasR;
        __syncthreads();   // LDS ready
        // prefetch next tile while computing this one
        if (t + 1 < ntiles) {
            const __bf16* ks = kbase + (size_t)(cbase + 64) * HDP;
            rk[0] = *reinterpret_cast<const bf16x8*>(ks + tid * 8);
            rk[1] = *reinterpret_cast<const bf16x8*>(ks + (tid + 256) * 8);
            { int d = tid >> 3, c8 = tid & 7;
              rv[0] = *reinterpret_cast<const bf16x8*>(vbase + (size_t)d * LK + cbase + 64 + c8 * 8); }
            if (tid < 176) { int c = tid + 256, d = c >> 3, c8 = c & 7;
              rv[1] = *reinterpret_cast<const bf16x8*>(vbase + (size_t)d * LK + cbase + 64 + c8 * 8); }
            if (tid < 64) biasR = bias[b * LK + cbase + 64 + tid];
        }

        // S = Q K^T
        f32x4 S[4];
        #pragma unroll
        for (int nt = 0; nt < 4; ++nt) {
            int krow = nt * 16 + l15, s = (krow & 7) << 3;
            bf16x8 b0 = *reinterpret_cast<const bf16x8*>(&Ks[krow * 64 + ((l4 * 8) ^ s)]);
            bf16x8 b1 = *reinterpret_cast<const bf16x8*>(&Ks[krow * 64 + ((32 + l4 * 8) ^ s)]);
            f32x4 acc = (f32x4){0.f, 0.f, 0.f, 0.f};
            acc = __builtin_amdgcn_mfma_f32_16x16x32_bf16(aQ[0], b0, acc, 0, 0, 0);
            acc = __builtin_amdgcn_mfma_f32_16x16x32_bf16(aQ[1], b1, acc, 0, 0, 0);
            S[nt] = acc;
        }
        // masks
        #pragma unroll
        for (int nt = 0; nt < 4; ++nt) {
            int cg = cbase + nt * 16 + l15;
            float bv = biasS[nt * 16 + l15];
            #pragma unroll
            for (int r = 0; r < 4; ++r) {
                float sv = S[nt][r] + bv;
                S[nt][r] = (cg > rgbase + r + M_) ? -1e30f : sv;
            }
        }
        // online softmax
        float mt[4], alpha[4], ls[4];
        #pragma unroll
        for (int r = 0; r < 4; ++r)
            mt[r] = fmaxf(fmaxf(S[0][r], S[1][r]), fmaxf(S[2][r], S[3][r]));
        #pragma unroll
        for (int r = 0; r < 4; ++r) {
            mt[r] = fmaxf(mt[r], __shfl_xor(mt[r], 1));
            mt[r] = fmaxf(mt[r], __shfl_xor(mt[r], 2));
            mt[r] = fmaxf(mt[r], __shfl_xor(mt[r], 4));
            mt[r] = fmaxf(mt[r], __shfl_xor(mt[r], 8));
            float m_new = fmaxf(m_run[r], mt[r]);
            alpha[r] = __expf(m_run[r] - m_new);
            m_run[r] = m_new;
            ls[r] = 0.f;
        }
        #pragma unroll
        for (int nt = 0; nt < 4; ++nt)
            #pragma unroll
            for (int r = 0; r < 4; ++r) {
                float p = __expf(S[nt][r] - m_run[r]);
                S[nt][r] = p;
                ls[r] += p;
            }
        #pragma unroll
        for (int r = 0; r < 4; ++r) {
            ls[r] += __shfl_xor(ls[r], 1);
            ls[r] += __shfl_xor(ls[r], 2);
            ls[r] += __shfl_xor(ls[r], 4);
            ls[r] += __shfl_xor(ls[r], 8);
            l_run[r] = l_run[r] * alpha[r] + ls[r];
        }
        // P -> LDS (wave-private strip, no barrier needed)
        #pragma unroll
        for (int r = 0; r < 4; ++r) {
            int row = 16 * w + l4 * 4 + r, s = (row & 7) << 3;
            #pragma unroll
            for (int nt = 0; nt < 4; ++nt) {
                int col = nt * 16 + l15;
                Ps[row * 64 + (col ^ s)] = (__bf16)S[nt][r];
            }
        }
        #pragma unroll
        for (int nt = 0; nt < 4; ++nt)
            #pragma unroll
            for (int r = 0; r < 4; ++r) Oacc[nt][r] *= alpha[r];
        // PV
        bf16x8 aP[2];
        {
            int prow = 16 * w + l15, s = (prow & 7) << 3;
            aP[0] = *reinterpret_cast<const bf16x8*>(&Ps[prow * 64 + ((l4 * 8) ^ s)]);
            aP[1] = *reinterpret_cast<const bf16x8*>(&Ps[prow * 64 + ((32 + l4 * 8) ^ s)]);
        }
        #pragma unroll
        for (int nt = 0; nt < 4; ++nt) {
            int vrow = nt * 16 + l15, s = (vrow & 7) << 3;
            bf16x8 v0 = *reinterpret_cast<const bf16x8*>(&Vs[vrow * 64 + ((l4 * 8) ^ s)]);
            bf16x8 v1 = *reinterpret_cast<const bf16x8*>(&Vs[vrow * 64 + ((32 + l4 * 8) ^ s)]);
            Oacc[nt] = __builtin_amdgcn_mfma_f32_16x16x32_bf16(aP[0], v0, Oacc[nt], 0, 0, 0);
            Oacc[nt] = __builtin_amdgcn_mfma_f32_16x16x32_bf16(aP[1], v1, Oacc[nt], 0, 0, 0);
        }
    }

    // epilogue: normalize, write bf16 into padded [8192][256] buffer
    float invl[4];
    #pragma unroll
    for (int r = 0; r < 4; ++r) invl[r] = 1.f / l_run[r];
    #pragma unroll
    for (int nt = 0; nt < 4; ++nt) {
        int c = nt * 16 + l15;
        if (c < HD) {
            #pragma unroll
            for (int r = 0; r < 4; ++r)
                aoutb[((size_t)b * L_ + rgbase + r) * KP + h * HD + c] =
                    (__bf16)(Oacc[nt][r] * invl[r]);
        }
    }
}

// ---------------------------------------------------------------------------
extern "C" void kernel_launch(void* const* d_in, const int* in_sizes, int n_in,
                              void* d_out, int out_size, void* d_ws, size_t ws_size,
                              hipStream_t stream) {
    const float* x     = (const float*)d_in[0];
    const float* mem_k = (const float*)d_in[1];
    const float* mem_v = (const float*)d_in[2];
    const int*   amask = (const int*)d_in[3];
    const float* Wqkv  = (const float*)d_in[4];
    const float* Wo    = (const float*)d_in[5];
    float* out = (float*)d_out;

    char* p = (char*)d_ws;
    float* qkv_raw = (float*)p;        p += (size_t)8192 * 648 * 4;
    float* bias    = (float*)p;        p += (size_t)B_ * LK * 4;
    __bf16* xb     = (__bf16*)p;       p += (size_t)8192 * KP * 2;
    __bf16* wqkvt  = (__bf16*)p;       p += (size_t)704 * KP * 2;
    __bf16* wot    = (__bf16*)p;       p += (size_t)256 * KP * 2;
    __bf16* aoutb  = (__bf16*)p;       p += (size_t)8192 * KP * 2;
    __bf16* qb     = (__bf16*)p;       p += (size_t)16 * 2048 * 64 * 2;
    __bf16* kall   = (__bf16*)p;       p += (size_t)16 * 2112 * 64 * 2;
    __bf16* vt     = (__bf16*)p;       p += (size_t)16 * 54 * 2112 * 2;

    conv_x<<<dim3(8192 * 32 / 256), 256, 0, stream>>>(x, xb);
    conv_wt<<<dim3(704), 256, 0, stream>>>(Wqkv, wqkvt, 216, 648, 704);
    conv_wt<<<dim3(256), 256, 0, stream>>>(Wo, wot, 216, 216, 256);

    // qkv = x @ Wqkv  (fp32 out for RoPE precision)
    gemm_mfma<<<dim3(11, 64), 256, 0, stream>>>(xb, wqkvt, qkv_raw, 648);

    memkv_pack<<<dim3((B_ * M_ * H_ * 64 + 255) / 256), 256, 0, stream>>>(mem_k, mem_v, kall, vt);
    rope_pack<<<dim3(B_ * L_), 128, 0, stream>>>(qkv_raw, qb, kall);
    transpose_v<<<dim3(L_ / 64, B_), 256, 0, stream>>>(qkv_raw, vt);
    mask_bias<<<dim3((B_ * LK + 255) / 256), 256, 0, stream>>>(amask, bias);

    hipMemsetAsync(aoutb, 0, (size_t)8192 * KP * 2, stream);  // zero K-pad cols
    flash_mfma<<<dim3(32, 16), 256, 0, stream>>>(qb, kall, vt, bias, aoutb);

    // out = aout @ Wo
    gemm_mfma<<<dim3(4, 64), 256, 0, stream>>>(aoutb, wot, out, 216);
}

// Round 4
// 116.007 us; speedup vs baseline: 5.9743x; 1.0049x over previous
//
#include <hip/hip_runtime.h>
#include <math.h>

#define B_ 4
#define L_ 2048
#define D_ 216
#define H_ 4
#define HD 54
#define HDP 64
#define M_ 64
#define LK 2112
#define NT_ 33   // LK/64 col-tiles
#define KP 256   // padded K for MFMA GEMMs

typedef __attribute__((ext_vector_type(8))) __bf16 bf16x8;
typedef __attribute__((ext_vector_type(4))) __bf16 bf16x4;
typedef __attribute__((ext_vector_type(4))) float f32x4;

// ---------------------------------------------------------------------------
// x [8192][216] fp32 -> xb [8192][256] bf16 (zero-padded)
// ---------------------------------------------------------------------------
__global__ void conv_x(const float* __restrict__ x, __bf16* __restrict__ xb) {
    int idx = blockIdx.x * 256 + threadIdx.x;
    int row = idx >> 5, c8 = idx & 31;
    bf16x8 v{};
    if (c8 < 27) {
        const float* p = x + (size_t)row * 216 + c8 * 8;
        #pragma unroll
        for (int j = 0; j < 8; ++j) v[j] = (__bf16)p[j];
    }
    *reinterpret_cast<bf16x8*>(xb + (size_t)row * KP + c8 * 8) = v;
}

// ---------------------------------------------------------------------------
// W [Kin][Nin] fp32 -> Wt [Npad][256] bf16 transposed, zero-padded
// ---------------------------------------------------------------------------
__global__ void conv_wt(const float* __restrict__ W, __bf16* __restrict__ Wt,
                        int Kin, int Nin, int Npad) {
    int idx = blockIdx.x * 256 + threadIdx.x;
    if (idx >= Npad * KP) return;
    int n = idx >> 8, k = idx & 255;
    float v = (n < Nin && k < Kin) ? W[(size_t)k * Nin + n] : 0.f;
    Wt[idx] = (__bf16)v;
}

// ---------------------------------------------------------------------------
// bf16 MFMA GEMM: C[8192][N] fp32 = A[8192][256] @ Bt[Npad][256]^T
// ---------------------------------------------------------------------------
__global__ __launch_bounds__(256) void gemm_mfma(const __bf16* __restrict__ A,
                                                 const __bf16* __restrict__ Bt,
                                                 float* __restrict__ C, int N) {
    __shared__ __align__(16) __bf16 As[8192];
    __shared__ __align__(16) __bf16 Bs[4096];
    const int col0 = blockIdx.x * 64;
    const int row0 = blockIdx.y * 128;
    const int tid = threadIdx.x;
    const int lane = tid & 63;
    const int w = tid >> 6, wm = w >> 1, wn = w & 1;
    const int l15 = lane & 15, l4 = lane >> 4;

    f32x4 acc[4][2];
    #pragma unroll
    for (int m = 0; m < 4; ++m)
        #pragma unroll
        for (int n = 0; n < 2; ++n) acc[m][n] = (f32x4){0.f, 0.f, 0.f, 0.f};

    bf16x8 ra[4], rb[2];
    #pragma unroll
    for (int i = 0; i < 4; ++i) { int c = tid + 256 * i, r = c >> 3, c8 = c & 7;
        ra[i] = *reinterpret_cast<const bf16x8*>(A + (size_t)(row0 + r) * KP + c8 * 8); }
    #pragma unroll
    for (int i = 0; i < 2; ++i) { int c = tid + 256 * i, r = c >> 3, c8 = c & 7;
        rb[i] = *reinterpret_cast<const bf16x8*>(Bt + (size_t)(col0 + r) * KP + c8 * 8); }

    for (int kit = 0; kit < 4; ++kit) {
        __syncthreads();
        #pragma unroll
        for (int i = 0; i < 4; ++i) { int c = tid + 256 * i, r = c >> 3, c8 = c & 7;
            *reinterpret_cast<bf16x8*>(&As[r * 64 + ((c8 ^ (r & 7)) * 8)]) = ra[i]; }
        #pragma unroll
        for (int i = 0; i < 2; ++i) { int c = tid + 256 * i, r = c >> 3, c8 = c & 7;
            *reinterpret_cast<bf16x8*>(&Bs[r * 64 + ((c8 ^ (r & 7)) * 8)]) = rb[i]; }
        __syncthreads();
        if (kit < 3) {
            const int k0 = (kit + 1) * 64;
            #pragma unroll
            for (int i = 0; i < 4; ++i) { int c = tid + 256 * i, r = c >> 3, c8 = c & 7;
                ra[i] = *reinterpret_cast<const bf16x8*>(A + (size_t)(row0 + r) * KP + k0 + c8 * 8); }
            #pragma unroll
            for (int i = 0; i < 2; ++i) { int c = tid + 256 * i, r = c >> 3, c8 = c & 7;
                rb[i] = *reinterpret_cast<const bf16x8*>(Bt + (size_t)(col0 + r) * KP + k0 + c8 * 8); }
        }
        #pragma unroll
        for (int ks = 0; ks < 2; ++ks) {
            bf16x8 af[4], bfr[2];
            #pragma unroll
            for (int m = 0; m < 4; ++m) { int row = wm * 64 + m * 16 + l15; int ch = ks * 4 + l4;
                af[m] = *reinterpret_cast<const bf16x8*>(&As[row * 64 + ((ch ^ (row & 7)) * 8)]); }
            #pragma unroll
            for (int n = 0; n < 2; ++n) { int row = wn * 32 + n * 16 + l15; int ch = ks * 4 + l4;
                bfr[n] = *reinterpret_cast<const bf16x8*>(&Bs[row * 64 + ((ch ^ (row & 7)) * 8)]); }
            #pragma unroll
            for (int m = 0; m < 4; ++m)
                #pragma unroll
                for (int n = 0; n < 2; ++n)
                    acc[m][n] = __builtin_amdgcn_mfma_f32_16x16x32_bf16(af[m], bfr[n], acc[m][n], 0, 0, 0);
        }
    }
    #pragma unroll
    for (int m = 0; m < 4; ++m)
        #pragma unroll
        for (int n = 0; n < 2; ++n) {
            int cc = col0 + wn * 32 + n * 16 + l15;
            if (cc < N) {
                #pragma unroll
                for (int rr = 0; rr < 4; ++rr)
                    C[(size_t)(row0 + wm * 64 + m * 16 + l4 * 4 + rr) * N + cc] = acc[m][n][rr];
            }
        }
}

// ---------------------------------------------------------------------------
__global__ void memkv_pack(const float* __restrict__ mk, const float* __restrict__ mv,
                           __bf16* __restrict__ kall, __bf16* __restrict__ vt) {
    int idx = blockIdx.x * 256 + threadIdx.x;
    if (idx >= B_ * M_ * H_ * 64) return;
    int b  = idx >> 14;
    int m  = (idx >> 8) & 63;
    int h  = (idx >> 6) & 3;
    int dd = idx & 63;
    float kv = (dd < HD) ? mk[((size_t)(b * M_ + m)) * D_ + h * HD + dd] : 0.f;
    kall[((size_t)(b * 4 + h) * LK + m) * HDP + dd] = (__bf16)kv;
    if (dd < HD)
        vt[((size_t)(b * 4 + h) * HD + dd) * LK + m] =
            (__bf16)mv[((size_t)(b * M_ + m)) * D_ + h * HD + dd];
}

// ---------------------------------------------------------------------------
// RoPE. Q pre-scaled by 54^-0.5 * log2(e)  (exp2-domain softmax).
// ---------------------------------------------------------------------------
__global__ __launch_bounds__(128) void rope_pack(const float* __restrict__ qkv,
                                                 __bf16* __restrict__ qb,
                                                 __bf16* __restrict__ kall) {
    const int blk = blockIdx.x;
    const int b = blk / L_, l = blk % L_;
    const float* row = qkv + (size_t)blk * 648;
    const int t = threadIdx.x;
    const float scale = 0.19632593f;  // 54^-0.5 * log2(e)
    if (t < 108) {
        int h = t / 27, ii = t % 27;
        float inv = exp2f(-0.49213749924f * (float)ii);  // 10000^(-2i/54)
        float ang = (float)l * inv;
        float s = sinf(ang), c = cosf(ang);
        float q0v = row[h * HD + ii], q1v = row[h * HD + ii + 27];
        float k0v = row[D_ + h * HD + ii], k1v = row[D_ + h * HD + ii + 27];
        size_t qoff = ((size_t)(b * 4 + h) * L_ + l) * HDP;
        qb[qoff + ii]      = (__bf16)((q0v * c - q1v * s) * scale);
        qb[qoff + ii + 27] = (__bf16)((q1v * c + q0v * s) * scale);
        size_t koff = ((size_t)(b * 4 + h) * LK + M_ + l) * HDP;
        kall[koff + ii]      = (__bf16)(k0v * c - k1v * s);
        kall[koff + ii + 27] = (__bf16)(k1v * c + k0v * s);
    }
    for (int p = t; p < 40; p += 128) {
        int h = p / 10, dd = 54 + p % 10;
        qb[((size_t)(b * 4 + h) * L_ + l) * HDP + dd] = (__bf16)0.f;
        kall[((size_t)(b * 4 + h) * LK + M_ + l) * HDP + dd] = (__bf16)0.f;
    }
}

// ---------------------------------------------------------------------------
__global__ __launch_bounds__(256) void transpose_v(const float* __restrict__ qkv,
                                                   __bf16* __restrict__ vt) {
    const int l0 = blockIdx.x * 64;
    const int b = blockIdx.y;
    __shared__ float T[64][55];
    for (int h = 0; h < 4; ++h) {
        __syncthreads();
        for (int idx = threadIdx.x; idx < 64 * 54; idx += 256) {
            int l = idx / 54, d = idx % 54;
            T[l][d] = qkv[((size_t)(b * L_ + l0 + l)) * 648 + 432 + h * 54 + d];
        }
        __syncthreads();
        for (int idx = threadIdx.x; idx < 54 * 64; idx += 256) {
            int d = idx >> 6, l = idx & 63;
            vt[((size_t)(b * 4 + h) * HD + d) * LK + M_ + l0 + l] = (__bf16)T[l][d];
        }
    }
}

// ---------------------------------------------------------------------------
// bias [B, LK] (0 / -1e30) + per-64-col-tile "has padding" flags [B, 33]
// ---------------------------------------------------------------------------
__global__ void mask_bias(const int* __restrict__ amask, float* __restrict__ bias) {
    int idx = blockIdx.x * 256 + threadIdx.x;
    if (idx >= B_ * LK) return;
    int b = idx / LK, c = idx % LK;
    bias[idx] = (c < M_ || amask[b * L_ + c - M_] != 0) ? 0.f : -1e30f;
}

__global__ void pad_flags(const int* __restrict__ amask, int* __restrict__ padflag) {
    int t = threadIdx.x;
    if (t >= B_ * NT_) return;
    int b = t / NT_, tile = t % NT_;
    int flag = 0;
    for (int u = 0; u < 64; ++u) {
        int c = tile * 64 + u;
        if (c >= M_ && amask[b * L_ + c - M_] == 0) flag = 1;
    }
    padflag[t] = flag;
}

// ---------------------------------------------------------------------------
// MFMA flash attention, swapped-QK^T softmax (lane owns one q-row).
// ---------------------------------------------------------------------------
__global__ __launch_bounds__(256) void flash_mfma(const __bf16* __restrict__ qb,
                                                  const __bf16* __restrict__ kall,
                                                  const __bf16* __restrict__ vt,
                                                  const float* __restrict__ bias,
                                                  const int* __restrict__ padflag,
                                                  __bf16* __restrict__ aoutb) {
    const int qt = (blockIdx.y & 8) ? (31 - (int)blockIdx.x) : (int)blockIdx.x;
    const int q0 = qt * 64;
    const int bh = blockIdx.y;
    const int b = bh >> 2, h = bh & 3;
    __shared__ __align__(16) __bf16 Qs[4096];
    __shared__ __align__(16) __bf16 Ks[4096];
    __shared__ __align__(16) __bf16 Vs[4096];
    __shared__ __align__(16) __bf16 Ps[4096];
    __shared__ float biasS[64];

    const int tid = threadIdx.x;
    const int lane = tid & 63;
    const int w = tid >> 6;
    const int l15 = lane & 15;
    const int l4 = lane >> 4;

    {   // stage Q (swizzled) + zero V pad rows
        const __bf16* src = qb + ((size_t)bh * L_ + q0) * HDP;
        for (int ch = tid; ch < 512; ch += 256) {
            int row = ch >> 3, c8 = ch & 7;
            bf16x8 v = *reinterpret_cast<const bf16x8*>(src + ch * 8);
            *reinterpret_cast<bf16x8*>(&Qs[row * 64 + ((c8 ^ (row & 7)) * 8)]) = v;
        }
        if (tid < 80) {
            int d = 54 + (tid >> 3), c8 = tid & 7;
            bf16x8 z{};
            *reinterpret_cast<bf16x8*>(&Vs[d * 64 + ((c8 ^ (d & 7)) * 8)]) = z;
        }
    }

    const int ntiles = qt + 2;
    const int rq = q0 + 16 * w + l15;   // q-row this lane reduces (softmax space)
    const __bf16* kbase = kall + (size_t)bh * LK * HDP;
    const __bf16* vbase = vt + (size_t)bh * HD * LK;

    // prefetch tile 0
    bf16x8 rk[2], rv[2];
    float biasR = 0.f;
    int flagC;
    {
        rk[0] = *reinterpret_cast<const bf16x8*>(kbase + tid * 8);
        rk[1] = *reinterpret_cast<const bf16x8*>(kbase + (tid + 256) * 8);
        { int d = tid >> 3, c8 = tid & 7;
          rv[0] = *reinterpret_cast<const bf16x8*>(vbase + (size_t)d * LK + c8 * 8); }
        if (tid < 176) { int c = tid + 256, d = c >> 3, c8 = c & 7;
          rv[1] = *reinterpret_cast<const bf16x8*>(vbase + (size_t)d * LK + c8 * 8); }
        if (tid < 64) biasR = bias[b * LK + tid];
        flagC = padflag[b * NT_];
    }

    __syncthreads();
    bf16x8 aQ[2];
    {
        int qrow = 16 * w + l15, s = (qrow & 7) << 3;
        aQ[0] = *reinterpret_cast<const bf16x8*>(&Qs[qrow * 64 + ((l4 * 8) ^ s)]);
        aQ[1] = *reinterpret_cast<const bf16x8*>(&Qs[qrow * 64 + ((32 + l4 * 8) ^ s)]);
    }

    f32x4 Oacc[4];
    #pragma unroll
    for (int nt = 0; nt < 4; ++nt) Oacc[nt] = (f32x4){0.f, 0.f, 0.f, 0.f};
    float m_run = -1e30f, l_run = 0.f;

    for (int t = 0; t < ntiles; ++t) {
        const int cbase = t * 64;
        __syncthreads();
        // commit staged registers to LDS (swizzled)
        { int r = tid >> 3, c8 = tid & 7;
          *reinterpret_cast<bf16x8*>(&Ks[r * 64 + ((c8 ^ (r & 7)) * 8)]) = rk[0]; }
        { int c = tid + 256, r = c >> 3, c8 = c & 7;
          *reinterpret_cast<bf16x8*>(&Ks[r * 64 + ((c8 ^ (r & 7)) * 8)]) = rk[1]; }
        { int d = tid >> 3, c8 = tid & 7;
          *reinterpret_cast<bf16x8*>(&Vs[d * 64 + ((c8 ^ (d & 7)) * 8)]) = rv[0]; }
        if (tid < 176) { int c = tid + 256, d = c >> 3, c8 = c & 7;
          *reinterpret_cast<bf16x8*>(&Vs[d * 64 + ((c8 ^ (d & 7)) * 8)]) = rv[1]; }
        if (tid < 64) biasS[tid] = biasR;
        const int flag = flagC;
        __syncthreads();
        // prefetch next tile
        if (t + 1 < ntiles) {
            const __bf16* ks = kbase + (size_t)(cbase + 64) * HDP;
            rk[0] = *reinterpret_cast<const bf16x8*>(ks + tid * 8);
            rk[1] = *reinterpret_cast<const bf16x8*>(ks + (tid + 256) * 8);
            { int d = tid >> 3, c8 = tid & 7;
              rv[0] = *reinterpret_cast<const bf16x8*>(vbase + (size_t)d * LK + cbase + 64 + c8 * 8); }
            if (tid < 176) { int c = tid + 256, d = c >> 3, c8 = c & 7;
              rv[1] = *reinterpret_cast<const bf16x8*>(vbase + (size_t)d * LK + cbase + 64 + c8 * 8); }
            if (tid < 64) biasR = bias[b * LK + cbase + 64 + tid];
            flagC = padflag[b * NT_ + t + 1];
        }

        // S^T = K Q^T : operand-swapped MFMA, same fragment loads.
        // lane holds: q-row = rq (uniform), k-pos cg = cbase + nt*16 + l4*4 + r
        f32x4 S[4];
        #pragma unroll
        for (int nt = 0; nt < 4; ++nt) {
            int krow = nt * 16 + l15, s = (krow & 7) << 3;
            bf16x8 b0 = *reinterpret_cast<const bf16x8*>(&Ks[krow * 64 + ((l4 * 8) ^ s)]);
            bf16x8 b1 = *reinterpret_cast<const bf16x8*>(&Ks[krow * 64 + ((32 + l4 * 8) ^ s)]);
            f32x4 acc = (f32x4){0.f, 0.f, 0.f, 0.f};
            acc = __builtin_amdgcn_mfma_f32_16x16x32_bf16(b0, aQ[0], acc, 0, 0, 0);
            acc = __builtin_amdgcn_mfma_f32_16x16x32_bf16(b1, aQ[1], acc, 0, 0, 0);
            S[nt] = acc;
        }
        if (flag) {   // padding bias (rare; wave-uniform branch)
            #pragma unroll
            for (int nt = 0; nt < 4; ++nt)
                #pragma unroll
                for (int r = 0; r < 4; ++r)
                    S[nt][r] += biasS[nt * 16 + l4 * 4 + r];
        }
        if (t == ntiles - 1) {   // causal: only the diagonal tile
            #pragma unroll
            for (int nt = 0; nt < 4; ++nt)
                #pragma unroll
                for (int r = 0; r < 4; ++r) {
                    int cg = cbase + nt * 16 + l4 * 4 + r;
                    if (cg > rq + M_) S[nt][r] = -1e30f;
                }
        }
        // softmax for q-row rq (in-lane over 16 vals + 2 shfl)
        float mx = fmaxf(fmaxf(S[0][0], S[0][1]), fmaxf(S[0][2], S[0][3]));
        #pragma unroll
        for (int nt = 1; nt < 4; ++nt)
            mx = fmaxf(mx, fmaxf(fmaxf(S[nt][0], S[nt][1]), fmaxf(S[nt][2], S[nt][3])));
        mx = fmaxf(mx, __shfl_xor(mx, 16));
        mx = fmaxf(mx, __shfl_xor(mx, 32));
        float m_new = fmaxf(m_run, mx);
        float alpha = exp2f(m_run - m_new);
        m_run = m_new;
        float ls = 0.f;
        #pragma unroll
        for (int nt = 0; nt < 4; ++nt)
            #pragma unroll
            for (int r = 0; r < 4; ++r) {
                float p = exp2f(S[nt][r] - m_new);
                S[nt][r] = p;
                ls += p;
            }
        ls += __shfl_xor(ls, 16);
        ls += __shfl_xor(ls, 32);
        l_run = l_run * alpha + ls;
        // P -> Ps (wave-private strip): row = 16w+l15, cols nt*16+l4*4..+3, b64 stores
        {
            int prow = 16 * w + l15, s = (prow & 7) << 3;
            #pragma unroll
            for (int nt = 0; nt < 4; ++nt) {
                bf16x4 pk;
                pk[0] = (__bf16)S[nt][0]; pk[1] = (__bf16)S[nt][1];
                pk[2] = (__bf16)S[nt][2]; pk[3] = (__bf16)S[nt][3];
                *reinterpret_cast<bf16x4*>(&Ps[prow * 64 + ((nt * 16 + l4 * 4) ^ s)]) = pk;
            }
        }
        // alpha back to O-row space (O row = l4*4+r): 4 shfl
        float aO[4];
        #pragma unroll
        for (int r = 0; r < 4; ++r)
            aO[r] = __shfl(alpha, (lane & 0x30) | (l4 * 4 + r), 64);
        #pragma unroll
        for (int nt = 0; nt < 4; ++nt)
            #pragma unroll
            for (int r = 0; r < 4; ++r) Oacc[nt][r] *= aO[r];
        // PV (standard orientation)
        bf16x8 aP[2];
        {
            int prow = 16 * w + l15, s = (prow & 7) << 3;
            aP[0] = *reinterpret_cast<const bf16x8*>(&Ps[prow * 64 + ((l4 * 8) ^ s)]);
            aP[1] = *reinterpret_cast<const bf16x8*>(&Ps[prow * 64 + ((32 + l4 * 8) ^ s)]);
        }
        #pragma unroll
        for (int nt = 0; nt < 4; ++nt) {
            int vrow = nt * 16 + l15, s = (vrow & 7) << 3;
            bf16x8 v0 = *reinterpret_cast<const bf16x8*>(&Vs[vrow * 64 + ((l4 * 8) ^ s)]);
            bf16x8 v1 = *reinterpret_cast<const bf16x8*>(&Vs[vrow * 64 + ((32 + l4 * 8) ^ s)]);
            Oacc[nt] = __builtin_amdgcn_mfma_f32_16x16x32_bf16(aP[0], v0, Oacc[nt], 0, 0, 0);
            Oacc[nt] = __builtin_amdgcn_mfma_f32_16x16x32_bf16(aP[1], v1, Oacc[nt], 0, 0, 0);
        }
    }

    // epilogue: invl back to O-row space, write bf16 into padded [8192][256]
    float li = 1.f / l_run;
    float invl[4];
    #pragma unroll
    for (int r = 0; r < 4; ++r)
        invl[r] = __shfl(li, (lane & 0x30) | (l4 * 4 + r), 64);
    const int rgbase = q0 + 16 * w + l4 * 4;
    #pragma unroll
    for (int nt = 0; nt < 4; ++nt) {
        int c = nt * 16 + l15;
        if (c < HD) {
            #pragma unroll
            for (int r = 0; r < 4; ++r)
                aoutb[((size_t)b * L_ + rgbase + r) * KP + h * HD + c] =
                    (__bf16)(Oacc[nt][r] * invl[r]);
        }
    }
}

// ---------------------------------------------------------------------------
extern "C" void kernel_launch(void* const* d_in, const int* in_sizes, int n_in,
                              void* d_out, int out_size, void* d_ws, size_t ws_size,
                              hipStream_t stream) {
    const float* x     = (const float*)d_in[0];
    const float* mem_k = (const float*)d_in[1];
    const float* mem_v = (const float*)d_in[2];
    const int*   amask = (const int*)d_in[3];
    const float* Wqkv  = (const float*)d_in[4];
    const float* Wo    = (const float*)d_in[5];
    float* out = (float*)d_out;

    char* p = (char*)d_ws;
    float* qkv_raw = (float*)p;        p += (size_t)8192 * 648 * 4;
    float* bias    = (float*)p;        p += (size_t)B_ * LK * 4;
    int*   padflag = (int*)p;          p += (size_t)B_ * NT_ * 4;
    __bf16* xb     = (__bf16*)p;       p += (size_t)8192 * KP * 2;
    __bf16* wqkvt  = (__bf16*)p;       p += (size_t)704 * KP * 2;
    __bf16* wot    = (__bf16*)p;       p += (size_t)256 * KP * 2;
    __bf16* aoutb  = (__bf16*)p;       p += (size_t)8192 * KP * 2;
    __bf16* qb     = (__bf16*)p;       p += (size_t)16 * 2048 * 64 * 2;
    __bf16* kall   = (__bf16*)p;       p += (size_t)16 * 2112 * 64 * 2;
    __bf16* vt     = (__bf16*)p;       p += (size_t)16 * 54 * 2112 * 2;

    conv_x<<<dim3(8192 * 32 / 256), 256, 0, stream>>>(x, xb);
    conv_wt<<<dim3(704), 256, 0, stream>>>(Wqkv, wqkvt, 216, 648, 704);
    conv_wt<<<dim3(256), 256, 0, stream>>>(Wo, wot, 216, 216, 256);

    gemm_mfma<<<dim3(11, 64), 256, 0, stream>>>(xb, wqkvt, qkv_raw, 648);

    memkv_pack<<<dim3((B_ * M_ * H_ * 64 + 255) / 256), 256, 0, stream>>>(mem_k, mem_v, kall, vt);
    rope_pack<<<dim3(B_ * L_), 128, 0, stream>>>(qkv_raw, qb, kall);
    transpose_v<<<dim3(L_ / 64, B_), 256, 0, stream>>>(qkv_raw, vt);
    mask_bias<<<dim3((B_ * LK + 255) / 256), 256, 0, stream>>>(amask, bias);
    pad_flags<<<dim3(1), 256, 0, stream>>>(amask, padflag);

    flash_mfma<<<dim3(32, 16), 256, 0, stream>>>(qb, kall, vt, bias, padflag, aoutb);

    gemm_mfma<<<dim3(4, 64), 256, 0, stream>>>(aoutb, wot, out, 216);
}